// Round 1
// 294.034 us; speedup vs baseline: 1.0134x; 1.0134x over previous
//
#include <hip/hip_runtime.h>
#include <hip/hip_bf16.h>
#include <stdint.h>

// Problem constants: B=4, S=2048, H=1024
#define BATCH 4
#define SLEN  2048
#define HID   1024

typedef __attribute__((ext_vector_type(8))) short bfrag8;   // 8 bf16 (4 VGPRs)
typedef __attribute__((ext_vector_type(4))) float facc4;    // 4 fp32 acc
typedef __attribute__((ext_vector_type(4))) unsigned short us4;

__device__ __forceinline__ unsigned short f2b(float f) {
  union { float f; unsigned int i; } x; x.f = f;
  unsigned int r = x.i + 0x7FFFu + ((x.i >> 16) & 1u);  // RNE
  return (unsigned short)(r >> 16);
}

__device__ __forceinline__ void gl_lds16(const void* g, void* l) {
  __builtin_amdgcn_global_load_lds(
      (const __attribute__((address_space(1))) void*)g,
      (__attribute__((address_space(3))) void*)l, 16, 0, 0);
}

// ------------- fused fp32 -> bf16 cast of all six inputs + lsum zero -------
// NOT dead weight: bf16 staging lets every GEMM use global_load_lds (async
// direct-to-LDS DMA). r6 proved inline fp32 staging exposes full load
// latency — the cast pass pays for itself.
__global__ __launch_bounds__(256) void cast_all(
    const float* __restrict__ q, const float* __restrict__ k,
    const float* __restrict__ v, const float* __restrict__ wq,
    const float* __restrict__ wk, const float* __restrict__ wv,
    us4* __restrict__ dst, float* __restrict__ lsum) {
  if (blockIdx.x < 8) {
    float4 z = {0.f, 0.f, 0.f, 0.f};
    ((float4*)lsum)[blockIdx.x * 256 + threadIdx.x] = z;
  }
  const long i = (long)blockIdx.x * 256 + threadIdx.x;
  const long S1 = 2097152, S2 = 4194304, S3 = 6291456,
             S4 = 6553600, S5 = 6815744;
  const float4* src; long off;
  if (i < S2) {
    if (i < S1) { src = (const float4*)q;  off = i; }
    else        { src = (const float4*)k;  off = i - S1; }
  } else if (i < S3) { src = (const float4*)v;  off = i - S2; }
  else if   (i < S4) { src = (const float4*)wq; off = i - S3; }
  else if   (i < S5) { src = (const float4*)wk; off = i - S4; }
  else               { src = (const float4*)wv; off = i - S5; }
  float4 x = src[off];
  us4 o;
  o.x = f2b(x.x); o.y = f2b(x.y); o.z = f2b(x.z); o.w = f2b(x.w);
  dst[i] = o;
}

// ================= 256x256 / BK=64 deep-pipelined core ====================
// T2 (XOR-8 swizzle, carried from r5) + T3 (4 phases/K-tile) + T4 (counted
// vmcnt(4), never 0 in steady loop) + T5 (setprio around MFMA clusters).
// 8 waves = 2(M) x 4(N); per-wave output 128x64 = acc[8][4] of facc4.
// LDS 128 KiB: A[2buf][2half][128x64] + B[2buf][2half][128x64] bf16.
// Schedule (verified by slot/issue-order accounting):
//   tile t, phase 1: read A-frags m0..3 + B-frags n0..1 (12 ds_read_b128);
//                    stage B-half0(t+1)->nxt; barrier; MFMA Q(0,0); barrier
//   phase 2: read A m4..7 + B n2..3; stage B-half1(t+1)->nxt; barrier;
//                    MFMA Q(1,1); barrier
//   phase 3: stage A-half0(t+2)->cur (slots released after ph2); MFMA Q(0,1); barrier
//   phase 4: stage A-half1(t+2)->cur; MFMA Q(1,0); s_waitcnt vmcnt(4); barrier
// vmcnt(4) retires everything through B-half1(t+1) (in-order retirement),
// leaving only the two A-halves of t+2 in flight across the barrier.
__device__ __forceinline__ void core256(
    const unsigned short* __restrict__ A, const unsigned short* __restrict__ B,
    const int lda, const int ldb, const int NT,
    unsigned short* __restrict__ As, unsigned short* __restrict__ Bs,
    facc4 (&acc)[8][4]) {
  const int tid  = threadIdx.x;          // 0..511
  const int lane = tid & 63;
  const int wave = tid >> 6;             // 0..7
  const int wm = wave >> 2;              // 0..1
  const int wn = wave & 3;               // 0..3
  const int ln = lane & 15;
  const int lq = lane >> 4;
  const int swz = ln & 7;

  // staging geometry: element e = l*512 + tid; row = e>>3; 8 threads/row
  const int row0 = tid >> 3;             // 0..63 (second load covers +64)
  const int blk  = (tid & 7) ^ (row0 & 7);   // pre-swizzled source block
  const unsigned short* pA = A + (long)row0 * lda + blk * 8;
  const unsigned short* pB = B + (long)row0 * ldb + blk * 8;
  const long a64 = 64l * lda, b64 = 64l * ldb;
  unsigned short* dA = As + tid * 8;
  unsigned short* dB = Bs + tid * 8;

#define STG_A(h, b, t) do { const unsigned short* g_ = pA + (h) * (a64 * 2) + (long)(t) * 64; \
    gl_lds16(g_,       dA + (b) * 16384 + (h) * 8192); \
    gl_lds16(g_ + a64, dA + (b) * 16384 + (h) * 8192 + 4096); } while (0)
#define STG_B(h, b, t) do { const unsigned short* g_ = pB + (h) * (b64 * 2) + (long)(t) * 64; \
    gl_lds16(g_,       dB + (b) * 16384 + (h) * 8192); \
    gl_lds16(g_ + b64, dB + (b) * 16384 + (h) * 8192 + 4096); } while (0)

  // fragment-read offsets (shorts); row&7 == ln&7 so swizzle = ln&7
  const int o0 = (lq ^ swz) * 8;
  const int o1 = ((4 + lq) ^ swz) * 8;
  const int aOfs = wm * 8192 + ln * 64;
  const int bOfs = (wn >> 1) * 8192 + ((wn & 1) * 64 + ln) * 64;

  // prologue: tile0 fully -> buf0; tile1 A-halves -> buf1  (NT >= 2)
  STG_A(0, 0, 0); STG_A(1, 0, 0); STG_B(0, 0, 0); STG_B(1, 0, 0);
  STG_A(0, 1, 1); STG_A(1, 1, 1);
  asm volatile("s_waitcnt vmcnt(4)" ::: "memory");   // tile0 landed; A(1) in flight
  __builtin_amdgcn_s_barrier();

#define MFMA16(AF, BF, MOFS, NOFS)                                          \
  _Pragma("unroll") for (int m_ = 0; m_ < 4; ++m_)                          \
  _Pragma("unroll") for (int n_ = 0; n_ < 2; ++n_) {                        \
    acc[(MOFS) + m_][(NOFS) + n_] = __builtin_amdgcn_mfma_f32_16x16x32_bf16(\
        AF[m_][0], BF[n_][0], acc[(MOFS) + m_][(NOFS) + n_], 0, 0, 0);      \
    acc[(MOFS) + m_][(NOFS) + n_] = __builtin_amdgcn_mfma_f32_16x16x32_bf16(\
        AF[m_][1], BF[n_][1], acc[(MOFS) + m_][(NOFS) + n_], 0, 0, 0);      \
  }

  for (int t = 0; t < NT; ++t) {
    const int bu = t & 1, nx = bu ^ 1;
    const unsigned short* Ab = As + bu * 16384 + aOfs;
    const unsigned short* Bb = Bs + bu * 16384 + bOfs;
    bfrag8 a0[4][2], a1[4][2], b0[2][2], b1[2][2];

    // ---- phase 1: reads (A qm0 + B qn0), stage B0(t+1), MFMA Q(0,0)
#pragma unroll
    for (int m = 0; m < 4; ++m) {
      a0[m][0] = *(const bfrag8*)(Ab + m * 1024 + o0);
      a0[m][1] = *(const bfrag8*)(Ab + m * 1024 + o1);
    }
#pragma unroll
    for (int n = 0; n < 2; ++n) {
      b0[n][0] = *(const bfrag8*)(Bb + n * 1024 + o0);
      b0[n][1] = *(const bfrag8*)(Bb + n * 1024 + o1);
    }
    if (t + 1 < NT) STG_B(0, nx, t + 1);
    __builtin_amdgcn_s_barrier();
    __builtin_amdgcn_s_setprio(1);
    MFMA16(a0, b0, 0, 0)
    __builtin_amdgcn_s_setprio(0);
    __builtin_amdgcn_s_barrier();

    // ---- phase 2: reads (A qm1 + B qn1), stage B1(t+1), MFMA Q(1,1)
#pragma unroll
    for (int m = 0; m < 4; ++m) {
      a1[m][0] = *(const bfrag8*)(Ab + (4 + m) * 1024 + o0);
      a1[m][1] = *(const bfrag8*)(Ab + (4 + m) * 1024 + o1);
    }
#pragma unroll
    for (int n = 0; n < 2; ++n) {
      b1[n][0] = *(const bfrag8*)(Bb + (2 + n) * 1024 + o0);
      b1[n][1] = *(const bfrag8*)(Bb + (2 + n) * 1024 + o1);
    }
    if (t + 1 < NT) STG_B(1, nx, t + 1);
    __builtin_amdgcn_s_barrier();
    __builtin_amdgcn_s_setprio(1);
    MFMA16(a1, b1, 4, 2)
    __builtin_amdgcn_s_setprio(0);
    __builtin_amdgcn_s_barrier();   // cur-buf slots fully read past here

    // ---- phase 3: stage A0(t+2) into cur, MFMA Q(0,1)
    if (t + 2 < NT) STG_A(0, bu, t + 2);
    __builtin_amdgcn_s_setprio(1);
    MFMA16(a0, b1, 0, 2)
    __builtin_amdgcn_s_setprio(0);
    __builtin_amdgcn_s_barrier();

    // ---- phase 4: stage A1(t+2) into cur, MFMA Q(1,0), counted vmcnt
    if (t + 2 < NT) STG_A(1, bu, t + 2);
    __builtin_amdgcn_s_setprio(1);
    MFMA16(a1, b0, 4, 0)
    __builtin_amdgcn_s_setprio(0);
    if (t + 2 < NT) asm volatile("s_waitcnt vmcnt(4)" ::: "memory");
    else            asm volatile("s_waitcnt vmcnt(0)" ::: "memory");
    __builtin_amdgcn_s_barrier();
  }
#undef MFMA16
#undef STG_A
#undef STG_B
}

// ============ fused QKV projection on the 256^2 core: 384 jobs =============
// Jobs 0-127: Q=Xq.Wq^T (32x4 tiles); 128-255: K=Xk.Wk^T; 256-383:
// Vt=Wv.Xv^T (4x32 tiles, ldc 8192). XCD remap (384 = 8*48, bijective).
__global__ __launch_bounds__(512, 2) void proj3_256(
    const unsigned short* __restrict__ Xq, const unsigned short* __restrict__ Wqb,
    const unsigned short* __restrict__ Xk, const unsigned short* __restrict__ Wkb,
    const unsigned short* __restrict__ Xv, const unsigned short* __restrict__ Wvb,
    unsigned short* __restrict__ Qb, unsigned short* __restrict__ Kb,
    unsigned short* __restrict__ Vt) {
  extern __shared__ unsigned short smem[];
  unsigned short* As = smem;
  unsigned short* Bs = smem + 32768;

  const int pid = blockIdx.x;
  const int p2  = (pid & 7) * 48 + (pid >> 3);  // XCD-contiguous
  const int g   = p2 >> 7;                      // 0:Q 1:K 2:Vt
  const int within = p2 & 127;

  const unsigned short* A; const unsigned short* B; unsigned short* C;
  long bm, bn; int ldc_;
  if (g == 0)      { A = Xq;  B = Wqb; C = Qb; }
  else if (g == 1) { A = Xk;  B = Wkb; C = Kb; }
  else             { A = Wvb; B = Xv;  C = Vt; }
  if (g < 2) { bm = (long)(within >> 2) * 256; bn = (long)(within & 3)  * 256; ldc_ = 1024; }
  else       { bm = (long)(within >> 5) * 256; bn = (long)(within & 31) * 256; ldc_ = 8192; }

  facc4 acc[8][4] = {};
  core256(A + bm * 1024, B + bn * 1024, 1024, 1024, HID / 64, As, Bs, acc);

  // Epilogue: C/D layout col=lane&15, row=(lane>>4)*4+reg  [m89-verified]
  const int lane = threadIdx.x & 63, wave = threadIdx.x >> 6;
  const int wm = wave >> 2, wn = wave & 3;
  const int ln = lane & 15, lq = lane >> 4;
#pragma unroll
  for (int m = 0; m < 8; ++m)
#pragma unroll
    for (int n = 0; n < 4; ++n) {
      const long mm = bm + wm * 128 + m * 16 + lq * 4;
      const long nn = bn + wn * 64 + n * 16 + ln;
#pragma unroll
      for (int r = 0; r < 4; ++r)
        C[(mm + r) * (long)ldc_ + nn] = f2b(acc[m][n][r]);
    }
}

// ============ scores on the 256^2 core: P = exp(Q.K^T/32), lsum += ========
// 256 blocks total (8x8 tiles x 4 batches) = exactly 1 per CU.
__global__ __launch_bounds__(512, 2) void scores256(
    const unsigned short* __restrict__ Q, const unsigned short* __restrict__ Kb,
    unsigned short* __restrict__ P, float* __restrict__ lsum) {
  extern __shared__ unsigned short smem[];
  unsigned short* As = smem;
  unsigned short* Bs = smem + 32768;

  const long z = blockIdx.z;
  const int pid = blockIdx.y * 8 + blockIdx.x;
  const int p2  = (pid & 7) * 8 + (pid >> 3);   // XCD gets one bm row-panel
  const long bm = (long)(p2 >> 3) * 256;
  const long bn = (long)(p2 & 7) * 256;

  const long SH = (long)SLEN * HID, SS = (long)SLEN * SLEN;
  facc4 acc[8][4] = {};
  core256(Q + z * SH + bm * 1024, Kb + z * SH + bn * 1024, 1024, 1024,
          HID / 64, As, Bs, acc);

  unsigned short* Pz = P + z * SS;
  float* lz = lsum + z * SLEN;
  const int lane = threadIdx.x & 63, wave = threadIdx.x >> 6;
  const int wm = wave >> 2, wn = wave & 3;
  const int ln = lane & 15, lq = lane >> 4;
#pragma unroll
  for (int m = 0; m < 8; ++m) {
#pragma unroll
    for (int r = 0; r < 4; ++r) {
      const long q = bm + wm * 128 + m * 16 + lq * 4 + r;
      float rowsum = 0.f;
#pragma unroll
      for (int n = 0; n < 4; ++n) {
        const long kcol = bn + wn * 64 + n * 16 + ln;
        float e = __expf(acc[m][n][r] * 0.03125f);
        Pz[q * (long)SLEN + kcol] = f2b(e);
        rowsum += e;
      }
      rowsum += __shfl_xor(rowsum, 1, 64);
      rowsum += __shfl_xor(rowsum, 2, 64);
      rowsum += __shfl_xor(rowsum, 4, 64);
      rowsum += __shfl_xor(rowsum, 8, 64);
      if (ln == 0) atomicAdd(&lz[q], rowsum);
    }
  }
}

// ---------------- bf16 NT GEMM (r5-proven 128^2 core), PV mode only -------
// MODE 2 = fp32 out scaled by 1/lsum[row] (softmax denominator in PV).
// Kept on the 128^2 structure: at 256^2 PV would be 128 blocks (0.5/CU).
template <int MODE, typename OutT>
__global__ __launch_bounds__(256) void gemm_nt(
    const unsigned short* __restrict__ A, const unsigned short* __restrict__ B,
    OutT* __restrict__ C, int K, int lda, int ldb, int ldc,
    long aStrideZ, long bStrideZ, long cStrideZ, float alpha,
    float* __restrict__ lsum) {
  A += (long)blockIdx.z * aStrideZ;
  B += (long)blockIdx.z * bStrideZ;
  C += (long)blockIdx.z * cStrideZ;
  const long lz = (long)blockIdx.z * SLEN;

  const int nbm = gridDim.x, nbn = gridDim.y;
  const int nb  = nbm * nbn;
  const int pid = blockIdx.y * nbm + blockIdx.x;
  const int p2  = (pid & 7) * (nb >> 3) + (pid >> 3);
  const int GROUP = 4;
  const int gsize = GROUP * nbn;
  const int gid   = p2 / gsize;
  const int rem   = p2 - gid * gsize;
  const long bm = (long)(gid * GROUP + (rem & (GROUP - 1))) * 128;
  const long bn = (long)(rem >> 2) * 128;

  __shared__ __align__(16) unsigned short As[128 * 64];
  __shared__ __align__(16) unsigned short Bs[128 * 64];

  const int tid  = threadIdx.x;
  const int lane = tid & 63;
  const int wave = tid >> 6;
  const int wr   = (wave >> 1) * 64;
  const int wc   = (wave & 1) * 64;
  const int ln   = lane & 15;
  const int lq   = lane >> 4;
  const int swz  = ln & 7;

  facc4 acc[4][4] = {};

  const unsigned short* ap[4]; const unsigned short* bp[4];
  unsigned short* asd[4]; unsigned short* bsd[4];
#pragma unroll
  for (int j = 0; j < 4; ++j) {
    const int c   = j * 256 + tid;
    const int row = c >> 3;
    const int src = ((c & 7) ^ (row & 7)) * 8;
    ap[j]  = A + (bm + row) * (long)lda + src;
    bp[j]  = B + (bn + row) * (long)ldb + src;
    asd[j] = &As[c * 8];
    bsd[j] = &Bs[c * 8];
  }

  for (int k0 = 0; k0 < K; k0 += 64) {
#pragma unroll
    for (int j = 0; j < 4; ++j) { gl_lds16(ap[j], asd[j]); ap[j] += 64; }
#pragma unroll
    for (int j = 0; j < 4; ++j) { gl_lds16(bp[j], bsd[j]); bp[j] += 64; }
    __syncthreads();

#pragma unroll
    for (int kk = 0; kk < 2; ++kk) {
      bfrag8 af[4], bfr[4];
#pragma unroll
      for (int i = 0; i < 4; ++i)
        af[i] = *(const bfrag8*)&As[(wr + i * 16 + ln) * 64 + ((kk * 4 + lq) ^ swz) * 8];
#pragma unroll
      for (int j = 0; j < 4; ++j)
        bfr[j] = *(const bfrag8*)&Bs[(wc + j * 16 + ln) * 64 + ((kk * 4 + lq) ^ swz) * 8];
#pragma unroll
      for (int i = 0; i < 4; ++i)
#pragma unroll
        for (int j = 0; j < 4; ++j)
          acc[i][j] = __builtin_amdgcn_mfma_f32_16x16x32_bf16(af[i], bfr[j], acc[i][j], 0, 0, 0);
    }
    __syncthreads();
  }

  if constexpr (MODE == 1) {
#pragma unroll
    for (int i = 0; i < 4; ++i) {
#pragma unroll
      for (int r = 0; r < 4; ++r) {
        const long m = bm + wr + i * 16 + lq * 4 + r;
        float rowsum = 0.f;
#pragma unroll
        for (int j = 0; j < 4; ++j) {
          const long n = bn + wc + j * 16 + ln;
          float e = __expf(acc[i][j][r] * alpha);
          C[m * (long)ldc + n] = (OutT)f2b(e);
          rowsum += e;
        }
        rowsum += __shfl_xor(rowsum, 1, 64);
        rowsum += __shfl_xor(rowsum, 2, 64);
        rowsum += __shfl_xor(rowsum, 4, 64);
        rowsum += __shfl_xor(rowsum, 8, 64);
        if (ln == 0) atomicAdd(&lsum[lz + m], rowsum);
      }
    }
  } else {
    float inv[16];
#pragma unroll
    for (int i = 0; i < 4; ++i)
#pragma unroll
      for (int r = 0; r < 4; ++r)
        inv[i * 4 + r] = 1.0f / lsum[lz + bm + wr + i * 16 + lq * 4 + r];
#pragma unroll
    for (int i = 0; i < 4; ++i)
#pragma unroll
      for (int j = 0; j < 4; ++j) {
        const long m = bm + wr + i * 16 + lq * 4;
        const long n = bn + wc + j * 16 + ln;
#pragma unroll
        for (int r = 0; r < 4; ++r)
          ((float*)C)[(m + r) * (long)ldc + n] = acc[i][j][r] * inv[i * 4 + r];
      }
  }
}

extern "C" void kernel_launch(void* const* d_in, const int* in_sizes, int n_in,
                              void* d_out, int out_size, void* d_ws, size_t ws_size,
                              hipStream_t stream) {
  const float* q_in = (const float*)d_in[0];
  const float* k_in = (const float*)d_in[1];
  const float* v_in = (const float*)d_in[2];
  const float* wq   = (const float*)d_in[3];
  const float* wk   = (const float*)d_in[4];
  const float* wv   = (const float*)d_in[5];
  float* out = (float*)d_out;

  const long NXH = (long)BATCH * SLEN * HID;   // 8,388,608
  const long NW  = (long)HID * HID;            // 1,048,576
  const long SH  = (long)SLEN * HID;           // per-batch q/k/v stride
  const long SS  = (long)SLEN * SLEN;          // per-batch score stride

  unsigned short* ws = (unsigned short*)d_ws;
  unsigned short* Xq  = ws;              // cast dst region is contiguous Xq..Wvb
  unsigned short* Xk  = Xq  + NXH;
  unsigned short* Xv  = Xk  + NXH;
  unsigned short* Wqb = Xv  + NXH;
  unsigned short* Wkb = Wqb + NW;
  unsigned short* Wvb = Wkb + NW;
  unsigned short* Qb  = Wvb + NW;
  unsigned short* Kb  = Qb  + NXH;
  unsigned short* Vt  = Kb  + NXH;       // Vt[h][b*S+s], ld = 8192
  float*          lsum = (float*)(Vt + NXH);   // 8192 fp32 row sums
  unsigned short* P   = Xq;              // 16.8M elems, aliases Xq+Xk (dead by then)

  static bool attr_done = false;
  if (!attr_done) {
    hipFuncSetAttribute(reinterpret_cast<const void*>(proj3_256),
                        hipFuncAttributeMaxDynamicSharedMemorySize, 131072);
    hipFuncSetAttribute(reinterpret_cast<const void*>(scores256),
                        hipFuncAttributeMaxDynamicSharedMemorySize, 131072);
    attr_done = true;
  }

  // 1. fused cast (28.3M elems) + lsum zeroing
  cast_all<<<dim3(27648), dim3(256), 0, stream>>>(q_in, k_in, v_in, wq, wk, wv,
                                                  (us4*)ws, lsum);

  // 2. all three projections, 256^2 deep-pipelined core (384 blocks)
  proj3_256<<<dim3(384), dim3(512), 131072, stream>>>(
      Xq, Wqb, Xk, Wkb, Xv, Wvb, Qb, Kb, Vt);

  // 3. scores+exp+rowsums, 256^2 core (256 blocks = 1/CU)
  scores256<<<dim3(8, 8, BATCH), dim3(512), 131072, stream>>>(Qb, Kb, P, lsum);

  // 4. out[b][q][h] = (1/lsum[b,q]) * sum_k P[b,q,k] * Vt[h][b*S+k]
  gemm_nt<2, float><<<dim3(16, 8, BATCH), dim3(256), 0, stream>>>(
      P, Vt, out, SLEN, SLEN, BATCH * SLEN, HID, SS, SLEN, SH, 1.0f, lsum);
}

// Round 2
// 288.243 us; speedup vs baseline: 1.0338x; 1.0201x over previous
//
#include <hip/hip_runtime.h>
#include <hip/hip_bf16.h>
#include <stdint.h>

// Problem constants: B=4, S=2048, H=1024
#define BATCH 4
#define SLEN  2048
#define HID   1024

typedef __attribute__((ext_vector_type(8))) short bfrag8;   // 8 bf16 (4 VGPRs)
typedef __attribute__((ext_vector_type(4))) float facc4;    // 4 fp32 acc
typedef __attribute__((ext_vector_type(4))) unsigned short us4;

__device__ __forceinline__ unsigned short f2b(float f) {
  union { float f; unsigned int i; } x; x.f = f;
  unsigned int r = x.i + 0x7FFFu + ((x.i >> 16) & 1u);  // RNE
  return (unsigned short)(r >> 16);
}

__device__ __forceinline__ void gl_lds16(const void* g, void* l) {
  __builtin_amdgcn_global_load_lds(
      (const __attribute__((address_space(1))) void*)g,
      (__attribute__((address_space(3))) void*)l, 16, 0, 0);
}

// ------------- fused fp32 -> bf16 cast of all six inputs + lsum zero -------
__global__ __launch_bounds__(256) void cast_all(
    const float* __restrict__ q, const float* __restrict__ k,
    const float* __restrict__ v, const float* __restrict__ wq,
    const float* __restrict__ wk, const float* __restrict__ wv,
    us4* __restrict__ dst, float* __restrict__ lsum) {
  if (blockIdx.x < 8) {
    float4 z = {0.f, 0.f, 0.f, 0.f};
    ((float4*)lsum)[blockIdx.x * 256 + threadIdx.x] = z;
  }
  const long i = (long)blockIdx.x * 256 + threadIdx.x;
  const long S1 = 2097152, S2 = 4194304, S3 = 6291456,
             S4 = 6553600, S5 = 6815744;
  const float4* src; long off;
  if (i < S2) {
    if (i < S1) { src = (const float4*)q;  off = i; }
    else        { src = (const float4*)k;  off = i - S1; }
  } else if (i < S3) { src = (const float4*)v;  off = i - S2; }
  else if   (i < S4) { src = (const float4*)wq; off = i - S3; }
  else if   (i < S5) { src = (const float4*)wk; off = i - S4; }
  else               { src = (const float4*)wv; off = i - S5; }
  float4 x = src[off];
  us4 o;
  o.x = f2b(x.x); o.y = f2b(x.y); o.z = f2b(x.z); o.w = f2b(x.w);
  dst[i] = o;
}

// ================= 256x256 / BK=64 core, read-one-phase-ahead ==============
// r1 post-mortem: reads and their consuming MFMA in the SAME phase serialize
// (LDS flood -> lgkmcnt(0) -> MFMA burst; MfmaUtil 30%). This version decouples
// them: every MFMA cluster consumes frags read in an EARLIER phase; each
// phase issues reads for the NEXT cluster before its MFMAs, so the LDS pipe
// drains under the matrix pipe (both ~2.4k cyc/tile -> near-full overlap).
// Schedule per tile t (buffers: tile t in bu=t&1, t+1 in nx):
//  ph1: rd b1(t);                      MFMA Q00(a0,b0);              barrier
//  ph2: rd a1(t); stg B0(t+2)->bu;     MFMA Q01(a0,b1); vmcnt(2);    barrier
//  ph3: rd a0(t+1) nx; stg A0(t+2);    MFMA Q11(a1,b1);            (no barrier)
//  ph4: rd b0(t+1) nx; stg A1,B1(t+2); MFMA Q10(a1,b0);              barrier
// vmcnt(2) at ph2 retires all of tile t+1 (newest-after = B0(t+2)'s 2 loads),
// so ph3/ph4 reads of t+1 are safe after the ph2 barrier. Slot hazards: each
// A-slot's last read is ph2 (a1), each B-slot's is ph1 (b1); all overwrites
// are issued >=1 barrier later. Tail tiles use vmcnt(0). Full unroll (NT is
// compile-time) so the a0/b0 rotation is SSA-renamed, not scratch (rule #20).
template <int NT>
__device__ __forceinline__ void core256(
    const unsigned short* __restrict__ A, const unsigned short* __restrict__ B,
    const int lda, const int ldb,
    unsigned short* __restrict__ As, unsigned short* __restrict__ Bs,
    facc4 (&acc)[8][4]) {
  const int tid  = threadIdx.x;          // 0..511
  const int lane = tid & 63;
  const int wave = tid >> 6;             // 0..7
  const int wm = wave >> 2;              // 0..1
  const int wn = wave & 3;               // 0..3
  const int ln = lane & 15;
  const int lq = lane >> 4;
  const int swz = ln & 7;

  // staging geometry: 8 threads/row, XOR-8 pre-swizzled source (r5-proven)
  const int row0 = tid >> 3;             // 0..63 (second load covers +64)
  const int blk  = (tid & 7) ^ (row0 & 7);
  const unsigned short* pA = A + (long)row0 * lda + blk * 8;
  const unsigned short* pB = B + (long)row0 * ldb + blk * 8;
  const long a64 = 64l * lda, b64 = 64l * ldb;
  unsigned short* dA = As + tid * 8;
  unsigned short* dB = Bs + tid * 8;

#define STG_A(h, b, t) do { const unsigned short* g_ = pA + (h) * (a64 * 2) + (long)(t) * 64; \
    gl_lds16(g_,       dA + (b) * 16384 + (h) * 8192); \
    gl_lds16(g_ + a64, dA + (b) * 16384 + (h) * 8192 + 4096); } while (0)
#define STG_B(h, b, t) do { const unsigned short* g_ = pB + (h) * (b64 * 2) + (long)(t) * 64; \
    gl_lds16(g_,       dB + (b) * 16384 + (h) * 8192); \
    gl_lds16(g_ + b64, dB + (b) * 16384 + (h) * 8192 + 4096); } while (0)

  const int o0 = (lq ^ swz) * 8;
  const int o1 = ((4 + lq) ^ swz) * 8;
  const int aOfs = wm * 8192 + ln * 64;
  const int bOfs = (wn >> 1) * 8192 + ((wn & 1) * 64 + ln) * 64;

#define RD_A4(dst, bufb, mb) do { \
  _Pragma("unroll") for (int m_ = 0; m_ < 4; ++m_) { \
    dst[m_][0] = *(const bfrag8*)(As + (bufb) + aOfs + ((mb) + m_) * 1024 + o0); \
    dst[m_][1] = *(const bfrag8*)(As + (bufb) + aOfs + ((mb) + m_) * 1024 + o1); \
  } } while (0)
#define RD_B2(dst, bufb, nb) do { \
  _Pragma("unroll") for (int n_ = 0; n_ < 2; ++n_) { \
    dst[n_][0] = *(const bfrag8*)(Bs + (bufb) + bOfs + ((nb) + n_) * 1024 + o0); \
    dst[n_][1] = *(const bfrag8*)(Bs + (bufb) + bOfs + ((nb) + n_) * 1024 + o1); \
  } } while (0)

#define MFMAQ(AF, BF, MO, NO) do { \
  _Pragma("unroll") for (int m_ = 0; m_ < 4; ++m_) \
  _Pragma("unroll") for (int n_ = 0; n_ < 2; ++n_) { \
    acc[(MO)+m_][(NO)+n_] = __builtin_amdgcn_mfma_f32_16x16x32_bf16( \
        AF[m_][0], BF[n_][0], acc[(MO)+m_][(NO)+n_], 0, 0, 0); \
    acc[(MO)+m_][(NO)+n_] = __builtin_amdgcn_mfma_f32_16x16x32_bf16( \
        AF[m_][1], BF[n_][1], acc[(MO)+m_][(NO)+n_], 0, 0, 0); \
  } } while (0)

  bfrag8 a0[4][2], a1[4][2], b0[2][2], b1[2][2], a0n[4][2], b0n[2][2];

  // prologue: tiles 0,1 fully staged (issue order matters for vmcnt math)
  STG_B(0, 0, 0); STG_A(0, 0, 0); STG_A(1, 0, 0); STG_B(1, 0, 0);
  STG_B(0, 1, 1); STG_A(0, 1, 1); STG_A(1, 1, 1); STG_B(1, 1, 1);
  asm volatile("s_waitcnt vmcnt(8)" ::: "memory");   // tile0 landed; tile1 in flight
  __builtin_amdgcn_s_barrier();
  RD_A4(a0, 0, 0);
  RD_B2(b0, 0, 0);

#pragma unroll
  for (int t = 0; t < NT; ++t) {
    const int bb = (t & 1) * 16384;
    const int nb = bb ^ 16384;

    // ---- phase 1: rd b1(t) for ph2/ph3; MFMA Q(0,0)
    RD_B2(b1, bb, 2);
    __builtin_amdgcn_s_setprio(1);
    MFMAQ(a0, b0, 0, 0);
    __builtin_amdgcn_s_setprio(0);
    __builtin_amdgcn_s_barrier();

    // ---- phase 2: rd a1(t); stage B0(t+2); MFMA Q(0,1); counted vmcnt
    RD_A4(a1, bb, 4);
    if (t + 2 < NT) STG_B(0, t & 1, t + 2);
    __builtin_amdgcn_s_setprio(1);
    MFMAQ(a0, b1, 0, 2);
    __builtin_amdgcn_s_setprio(0);
    if (t + 2 < NT) asm volatile("s_waitcnt vmcnt(2)" ::: "memory");
    else            asm volatile("s_waitcnt vmcnt(0)" ::: "memory");
    __builtin_amdgcn_s_barrier();    // tile t+1 now visible to all waves

    // ---- phase 3: rd a0(t+1); stage A0(t+2); MFMA Q(1,1)  (no barrier:
    //      ph4's writes hit slots last read before the ph2 barrier)
    if (t + 1 < NT) RD_A4(a0n, nb, 0);
    if (t + 2 < NT) STG_A(0, t & 1, t + 2);
    __builtin_amdgcn_s_setprio(1);
    MFMAQ(a1, b1, 4, 2);
    __builtin_amdgcn_s_setprio(0);

    // ---- phase 4: rd b0(t+1); stage A1,B1(t+2); MFMA Q(1,0)
    if (t + 1 < NT) RD_B2(b0n, nb, 0);
    if (t + 2 < NT) { STG_A(1, t & 1, t + 2); STG_B(1, t & 1, t + 2); }
    __builtin_amdgcn_s_setprio(1);
    MFMAQ(a1, b0, 4, 0);
    __builtin_amdgcn_s_setprio(0);
    __builtin_amdgcn_s_barrier();

    // rotate look-ahead frags (SSA under full unroll)
    if (t + 1 < NT) {
#pragma unroll
      for (int m_ = 0; m_ < 4; ++m_) { a0[m_][0] = a0n[m_][0]; a0[m_][1] = a0n[m_][1]; }
#pragma unroll
      for (int n_ = 0; n_ < 2; ++n_) { b0[n_][0] = b0n[n_][0]; b0[n_][1] = b0n[n_][1]; }
    }
  }
#undef MFMAQ
#undef RD_A4
#undef RD_B2
#undef STG_A
#undef STG_B
}

// ============ fused QKV projection on the 256^2 core: 384 jobs =============
__global__ __launch_bounds__(512, 2) void proj3_256(
    const unsigned short* __restrict__ Xq, const unsigned short* __restrict__ Wqb,
    const unsigned short* __restrict__ Xk, const unsigned short* __restrict__ Wkb,
    const unsigned short* __restrict__ Xv, const unsigned short* __restrict__ Wvb,
    unsigned short* __restrict__ Qb, unsigned short* __restrict__ Kb,
    unsigned short* __restrict__ Vt) {
  extern __shared__ unsigned short smem[];
  unsigned short* As = smem;
  unsigned short* Bs = smem + 32768;

  const int pid = blockIdx.x;
  const int p2  = (pid & 7) * 48 + (pid >> 3);  // XCD-contiguous (384 = 8*48)
  const int g   = p2 >> 7;                      // 0:Q 1:K 2:Vt
  const int within = p2 & 127;

  const unsigned short* A; const unsigned short* B; unsigned short* C;
  long bm, bn; int ldc_;
  if (g == 0)      { A = Xq;  B = Wqb; C = Qb; }
  else if (g == 1) { A = Xk;  B = Wkb; C = Kb; }
  else             { A = Wvb; B = Xv;  C = Vt; }
  if (g < 2) { bm = (long)(within >> 2) * 256; bn = (long)(within & 3)  * 256; ldc_ = 1024; }
  else       { bm = (long)(within >> 5) * 256; bn = (long)(within & 31) * 256; ldc_ = 8192; }

  facc4 acc[8][4] = {};
  core256<HID / 64>(A + bm * 1024, B + bn * 1024, 1024, 1024, As, Bs, acc);

  // Epilogue: C/D layout col=lane&15, row=(lane>>4)*4+reg  [m89-verified]
  const int lane = threadIdx.x & 63, wave = threadIdx.x >> 6;
  const int wm = wave >> 2, wn = wave & 3;
  const int ln = lane & 15, lq = lane >> 4;
#pragma unroll
  for (int m = 0; m < 8; ++m)
#pragma unroll
    for (int n = 0; n < 4; ++n) {
      const long mm = bm + wm * 128 + m * 16 + lq * 4;
      const long nn = bn + wn * 64 + n * 16 + ln;
#pragma unroll
      for (int r = 0; r < 4; ++r)
        C[(mm + r) * (long)ldc_ + nn] = f2b(acc[m][n][r]);
    }
}

// ============ scores on the 256^2 core: P = exp(Q.K^T/32), lsum += ========
__global__ __launch_bounds__(512, 2) void scores256(
    const unsigned short* __restrict__ Q, const unsigned short* __restrict__ Kb,
    unsigned short* __restrict__ P, float* __restrict__ lsum) {
  extern __shared__ unsigned short smem[];
  unsigned short* As = smem;
  unsigned short* Bs = smem + 32768;

  const long z = blockIdx.z;
  const int pid = blockIdx.y * 8 + blockIdx.x;
  const int p2  = (pid & 7) * 8 + (pid >> 3);   // XCD gets one bm row-panel
  const long bm = (long)(p2 >> 3) * 256;
  const long bn = (long)(p2 & 7) * 256;

  const long SH = (long)SLEN * HID, SS = (long)SLEN * SLEN;
  facc4 acc[8][4] = {};
  core256<HID / 64>(Q + z * SH + bm * 1024, Kb + z * SH + bn * 1024, 1024, 1024,
                    As, Bs, acc);

  unsigned short* Pz = P + z * SS;
  float* lz = lsum + z * SLEN;
  const int lane = threadIdx.x & 63, wave = threadIdx.x >> 6;
  const int wm = wave >> 2, wn = wave & 3;
  const int ln = lane & 15, lq = lane >> 4;
#pragma unroll
  for (int m = 0; m < 8; ++m) {
#pragma unroll
    for (int r = 0; r < 4; ++r) {
      const long q = bm + wm * 128 + m * 16 + lq * 4 + r;
      float rowsum = 0.f;
#pragma unroll
      for (int n = 0; n < 4; ++n) {
        const long kcol = bn + wn * 64 + n * 16 + ln;
        float e = __expf(acc[m][n][r] * 0.03125f);
        Pz[q * (long)SLEN + kcol] = f2b(e);
        rowsum += e;
      }
      rowsum += __shfl_xor(rowsum, 1, 64);
      rowsum += __shfl_xor(rowsum, 2, 64);
      rowsum += __shfl_xor(rowsum, 4, 64);
      rowsum += __shfl_xor(rowsum, 8, 64);
      if (ln == 0) atomicAdd(&lz[q], rowsum);
    }
  }
}

// ---------------- bf16 NT GEMM (r5-proven 128^2 core), PV only -------------
// MODE 2 = fp32 out scaled by 1/lsum[row]. Kept on 128^2: at 256^2 PV would
// be 128 blocks (0.5/CU) — no expected gain.
template <int MODE, typename OutT>
__global__ __launch_bounds__(256) void gemm_nt(
    const unsigned short* __restrict__ A, const unsigned short* __restrict__ B,
    OutT* __restrict__ C, int K, int lda, int ldb, int ldc,
    long aStrideZ, long bStrideZ, long cStrideZ, float alpha,
    float* __restrict__ lsum) {
  A += (long)blockIdx.z * aStrideZ;
  B += (long)blockIdx.z * bStrideZ;
  C += (long)blockIdx.z * cStrideZ;
  const long lz = (long)blockIdx.z * SLEN;

  const int nbm = gridDim.x, nbn = gridDim.y;
  const int nb  = nbm * nbn;
  const int pid = blockIdx.y * nbm + blockIdx.x;
  const int p2  = (pid & 7) * (nb >> 3) + (pid >> 3);
  const int GROUP = 4;
  const int gsize = GROUP * nbn;
  const int gid   = p2 / gsize;
  const int rem   = p2 - gid * gsize;
  const long bm = (long)(gid * GROUP + (rem & (GROUP - 1))) * 128;
  const long bn = (long)(rem >> 2) * 128;

  __shared__ __align__(16) unsigned short As[128 * 64];
  __shared__ __align__(16) unsigned short Bs[128 * 64];

  const int tid  = threadIdx.x;
  const int lane = tid & 63;
  const int wave = tid >> 6;
  const int wr   = (wave >> 1) * 64;
  const int wc   = (wave & 1) * 64;
  const int ln   = lane & 15;
  const int lq   = lane >> 4;
  const int swz  = ln & 7;

  facc4 acc[4][4] = {};

  const unsigned short* ap[4]; const unsigned short* bp[4];
  unsigned short* asd[4]; unsigned short* bsd[4];
#pragma unroll
  for (int j = 0; j < 4; ++j) {
    const int c   = j * 256 + tid;
    const int row = c >> 3;
    const int src = ((c & 7) ^ (row & 7)) * 8;
    ap[j]  = A + (bm + row) * (long)lda + src;
    bp[j]  = B + (bn + row) * (long)ldb + src;
    asd[j] = &As[c * 8];
    bsd[j] = &Bs[c * 8];
  }

  for (int k0 = 0; k0 < K; k0 += 64) {
#pragma unroll
    for (int j = 0; j < 4; ++j) { gl_lds16(ap[j], asd[j]); ap[j] += 64; }
#pragma unroll
    for (int j = 0; j < 4; ++j) { gl_lds16(bp[j], bsd[j]); bp[j] += 64; }
    __syncthreads();

#pragma unroll
    for (int kk = 0; kk < 2; ++kk) {
      bfrag8 af[4], bfr[4];
#pragma unroll
      for (int i = 0; i < 4; ++i)
        af[i] = *(const bfrag8*)&As[(wr + i * 16 + ln) * 64 + ((kk * 4 + lq) ^ swz) * 8];
#pragma unroll
      for (int j = 0; j < 4; ++j)
        bfr[j] = *(const bfrag8*)&Bs[(wc + j * 16 + ln) * 64 + ((kk * 4 + lq) ^ swz) * 8];
#pragma unroll
      for (int i = 0; i < 4; ++i)
#pragma unroll
        for (int j = 0; j < 4; ++j)
          acc[i][j] = __builtin_amdgcn_mfma_f32_16x16x32_bf16(af[i], bfr[j], acc[i][j], 0, 0, 0);
    }
    __syncthreads();
  }

  if constexpr (MODE == 1) {
#pragma unroll
    for (int i = 0; i < 4; ++i) {
#pragma unroll
      for (int r = 0; r < 4; ++r) {
        const long m = bm + wr + i * 16 + lq * 4 + r;
        float rowsum = 0.f;
#pragma unroll
        for (int j = 0; j < 4; ++j) {
          const long n = bn + wc + j * 16 + ln;
          float e = __expf(acc[i][j][r] * alpha);
          C[m * (long)ldc + n] = (OutT)f2b(e);
          rowsum += e;
        }
        rowsum += __shfl_xor(rowsum, 1, 64);
        rowsum += __shfl_xor(rowsum, 2, 64);
        rowsum += __shfl_xor(rowsum, 4, 64);
        rowsum += __shfl_xor(rowsum, 8, 64);
        if (ln == 0) atomicAdd(&lsum[lz + m], rowsum);
      }
    }
  } else {
    float inv[16];
#pragma unroll
    for (int i = 0; i < 4; ++i)
#pragma unroll
      for (int r = 0; r < 4; ++r)
        inv[i * 4 + r] = 1.0f / lsum[lz + bm + wr + i * 16 + lq * 4 + r];
#pragma unroll
    for (int i = 0; i < 4; ++i)
#pragma unroll
      for (int j = 0; j < 4; ++j) {
        const long m = bm + wr + i * 16 + lq * 4;
        const long n = bn + wc + j * 16 + ln;
#pragma unroll
        for (int r = 0; r < 4; ++r)
          ((float*)C)[(m + r) * (long)ldc + n] = acc[i][j][r] * inv[i * 4 + r];
      }
  }
}

extern "C" void kernel_launch(void* const* d_in, const int* in_sizes, int n_in,
                              void* d_out, int out_size, void* d_ws, size_t ws_size,
                              hipStream_t stream) {
  const float* q_in = (const float*)d_in[0];
  const float* k_in = (const float*)d_in[1];
  const float* v_in = (const float*)d_in[2];
  const float* wq   = (const float*)d_in[3];
  const float* wk   = (const float*)d_in[4];
  const float* wv   = (const float*)d_in[5];
  float* out = (float*)d_out;

  const long NXH = (long)BATCH * SLEN * HID;   // 8,388,608
  const long NW  = (long)HID * HID;            // 1,048,576
  const long SH  = (long)SLEN * HID;           // per-batch q/k/v stride
  const long SS  = (long)SLEN * SLEN;          // per-batch score stride

  unsigned short* ws = (unsigned short*)d_ws;
  unsigned short* Xq  = ws;              // cast dst region is contiguous Xq..Wvb
  unsigned short* Xk  = Xq  + NXH;
  unsigned short* Xv  = Xk  + NXH;
  unsigned short* Wqb = Xv  + NXH;
  unsigned short* Wkb = Wqb + NW;
  unsigned short* Wvb = Wkb + NW;
  unsigned short* Qb  = Wvb + NW;
  unsigned short* Kb  = Qb  + NXH;
  unsigned short* Vt  = Kb  + NXH;       // Vt[h][b*S+s], ld = 8192
  float*          lsum = (float*)(Vt + NXH);   // 8192 fp32 row sums
  unsigned short* P   = Xq;              // 16.8M elems, aliases Xq+Xk (dead by then)

  static bool attr_done = false;
  if (!attr_done) {
    hipFuncSetAttribute(reinterpret_cast<const void*>(proj3_256),
                        hipFuncAttributeMaxDynamicSharedMemorySize, 131072);
    hipFuncSetAttribute(reinterpret_cast<const void*>(scores256),
                        hipFuncAttributeMaxDynamicSharedMemorySize, 131072);
    attr_done = true;
  }

  // 1. fused cast (28.3M elems) + lsum zeroing
  cast_all<<<dim3(27648), dim3(256), 0, stream>>>(q_in, k_in, v_in, wq, wk, wv,
                                                  (us4*)ws, lsum);

  // 2. all three projections, 256^2 pipelined core (384 blocks)
  proj3_256<<<dim3(384), dim3(512), 131072, stream>>>(
      Xq, Wqb, Xk, Wkb, Xv, Wvb, Qb, Kb, Vt);

  // 3. scores+exp+rowsums, 256^2 core (256 blocks = 1/CU)
  scores256<<<dim3(8, 8, BATCH), dim3(512), 131072, stream>>>(Qb, Kb, P, lsum);

  // 4. out[b][q][h] = (1/lsum[b,q]) * sum_k P[b,q,k] * Vt[h][b*S+k]
  gemm_nt<2, float><<<dim3(16, 8, BATCH), dim3(256), 0, stream>>>(
      P, Vt, out, SLEN, SLEN, BATCH * SLEN, HID, SS, SLEN, SH, 1.0f, lsum);
}

// Round 3
// 283.322 us; speedup vs baseline: 1.0517x; 1.0174x over previous
//
#include <hip/hip_runtime.h>
#include <hip/hip_bf16.h>
#include <stdint.h>

// Problem constants: B=4, S=2048, H=1024
#define BATCH 4
#define SLEN  2048
#define HID   1024

typedef __attribute__((ext_vector_type(8))) short bfrag8;   // 8 bf16 (4 VGPRs)
typedef __attribute__((ext_vector_type(4))) float facc4;    // 4 fp32 acc
typedef __attribute__((ext_vector_type(4))) unsigned short us4;

__device__ __forceinline__ unsigned short f2b(float f) {
  union { float f; unsigned int i; } x; x.f = f;
  unsigned int r = x.i + 0x7FFFu + ((x.i >> 16) & 1u);  // RNE
  return (unsigned short)(r >> 16);
}

__device__ __forceinline__ void gl_lds16(const void* g, void* l) {
  __builtin_amdgcn_global_load_lds(
      (const __attribute__((address_space(1))) void*)g,
      (__attribute__((address_space(3))) void*)l, 16, 0, 0);
}

// ------------- fused fp32 -> bf16 cast of all six inputs + lsum zero -------
__global__ __launch_bounds__(256) void cast_all(
    const float* __restrict__ q, const float* __restrict__ k,
    const float* __restrict__ v, const float* __restrict__ wq,
    const float* __restrict__ wk, const float* __restrict__ wv,
    us4* __restrict__ dst, float* __restrict__ lsum) {
  if (blockIdx.x < 8) {
    float4 z = {0.f, 0.f, 0.f, 0.f};
    ((float4*)lsum)[blockIdx.x * 256 + threadIdx.x] = z;
  }
  const long i = (long)blockIdx.x * 256 + threadIdx.x;
  const long S1 = 2097152, S2 = 4194304, S3 = 6291456,
             S4 = 6553600, S5 = 6815744;
  const float4* src; long off;
  if (i < S2) {
    if (i < S1) { src = (const float4*)q;  off = i; }
    else        { src = (const float4*)k;  off = i - S1; }
  } else if (i < S3) { src = (const float4*)v;  off = i - S2; }
  else if   (i < S4) { src = (const float4*)wq; off = i - S3; }
  else if   (i < S5) { src = (const float4*)wk; off = i - S4; }
  else               { src = (const float4*)wv; off = i - S5; }
  float4 x = src[off];
  us4 o;
  o.x = f2b(x.x); o.y = f2b(x.y); o.z = f2b(x.z); o.w = f2b(x.w);
  dst[i] = o;
}

// ================= 256x256 / BK=64 core — m201-faithful 8-phase ===========
// r1/r2 post-mortem: both home-grown schedules land at ~30% MfmaUtil with
// ~3000 cyc/tile exposed stalls. This is the verified m201 cadence, ported
// verbatim: each phase = {ds-reads + 1 half-tile stage ISSUED first;
// mid-barrier; asm lgkmcnt(0); sched_barrier(0) [rule #18]; setprio(1);
// 16 MFMA; setprio(0); sched_barrier(0); end-barrier}. Counted vmcnt(4)
// only at ph4/ph8 (12 outstanding, retire 8, 4 stay in flight — never 0
// in the main loop). Iteration = 2 K-tiles: E=2i (buf0) ph1-4, O=2i+1
// (buf1) ph5-8. Stage slots (free-slot + landing deadlines hand-verified):
//   ph1:A0(O) ph2:A1(O) ph3:B0(E+2) ph4:B1(E+2)
//   ph5:A0(E+2) ph6:A1(E+2) ph7:B0(O+2) ph8:B1(O+2)
// vmcnt(4)@ph4 retires ..A1(O) -> tile O landed before ph5 reads;
// vmcnt(4)@ph8 retires ..A1(E+2) -> tile E+2 landed before next ph1.
// Last iteration peeled (no E+2/O+2 stages; vmcnt(0)@ph4).
template <int NT>
__device__ __forceinline__ void core256(
    const unsigned short* __restrict__ A, const unsigned short* __restrict__ B,
    const int lda, const int ldb,
    unsigned short* __restrict__ As, unsigned short* __restrict__ Bs,
    facc4 (&acc)[8][4]) {
  const int tid  = threadIdx.x;          // 0..511
  const int lane = tid & 63;
  const int wave = tid >> 6;             // 0..7
  const int wm = wave >> 2;              // 0..1
  const int wn = wave & 3;               // 0..3
  const int ln = lane & 15;
  const int lq = lane >> 4;
  const int swz = ln & 7;

  // staging geometry: 8 threads/row, XOR-8 pre-swizzled source (r5-proven,
  // bank-conflict counter = 0 in all rounds)
  const int row0 = tid >> 3;             // 0..63 (second load covers +64)
  const int blk  = (tid & 7) ^ (row0 & 7);
  const unsigned short* pA = A + (long)row0 * lda + blk * 8;
  const unsigned short* pB = B + (long)row0 * ldb + blk * 8;
  const long a64 = 64l * lda, b64 = 64l * ldb;
  unsigned short* dA = As + tid * 8;
  unsigned short* dB = Bs + tid * 8;

#define STG_A(h, b, t) do { const unsigned short* g_ = pA + (h) * (a64 * 2) + (long)(t) * 64; \
    gl_lds16(g_,       dA + (b) * 16384 + (h) * 8192); \
    gl_lds16(g_ + a64, dA + (b) * 16384 + (h) * 8192 + 4096); } while (0)
#define STG_B(h, b, t) do { const unsigned short* g_ = pB + (h) * (b64 * 2) + (long)(t) * 64; \
    gl_lds16(g_,       dB + (b) * 16384 + (h) * 8192); \
    gl_lds16(g_ + b64, dB + (b) * 16384 + (h) * 8192 + 4096); } while (0)

  const int o0 = (lq ^ swz) * 8;
  const int o1 = ((4 + lq) ^ swz) * 8;
  const int aOfs = wm * 8192 + ln * 64;
  const int bOfs = (wn >> 1) * 8192 + ((wn & 1) * 64 + ln) * 64;

#define RD_A4(dst, bufb, mb) do { \
  _Pragma("unroll") for (int m_ = 0; m_ < 4; ++m_) { \
    dst[m_][0] = *(const bfrag8*)(As + (bufb) + aOfs + ((mb) + m_) * 1024 + o0); \
    dst[m_][1] = *(const bfrag8*)(As + (bufb) + aOfs + ((mb) + m_) * 1024 + o1); \
  } } while (0)
#define RD_B2(dst, bufb, nb) do { \
  _Pragma("unroll") for (int n_ = 0; n_ < 2; ++n_) { \
    dst[n_][0] = *(const bfrag8*)(Bs + (bufb) + bOfs + ((nb) + n_) * 1024 + o0); \
    dst[n_][1] = *(const bfrag8*)(Bs + (bufb) + bOfs + ((nb) + n_) * 1024 + o1); \
  } } while (0)

#define MFMAQ(AF, BF, MO, NO) do { \
  _Pragma("unroll") for (int m_ = 0; m_ < 4; ++m_) \
  _Pragma("unroll") for (int n_ = 0; n_ < 2; ++n_) { \
    acc[(MO)+m_][(NO)+n_] = __builtin_amdgcn_mfma_f32_16x16x32_bf16( \
        AF[m_][0], BF[n_][0], acc[(MO)+m_][(NO)+n_], 0, 0, 0); \
    acc[(MO)+m_][(NO)+n_] = __builtin_amdgcn_mfma_f32_16x16x32_bf16( \
        AF[m_][1], BF[n_][1], acc[(MO)+m_][(NO)+n_], 0, 0, 0); \
  } } while (0)

#define PH_MID \
  __builtin_amdgcn_s_barrier(); \
  asm volatile("s_waitcnt lgkmcnt(0)" ::: "memory"); \
  __builtin_amdgcn_sched_barrier(0); \
  __builtin_amdgcn_s_setprio(1)
#define PH_END \
  __builtin_amdgcn_s_setprio(0); \
  __builtin_amdgcn_sched_barrier(0); \
  __builtin_amdgcn_s_barrier()

  // prologue: tile0 full -> buf0; tile1 B-halves -> buf1 (A-halves at ph1/2)
  STG_A(0, 0, 0); STG_A(1, 0, 0); STG_B(0, 0, 0); STG_B(1, 0, 0);
  STG_B(0, 1, 1); STG_B(1, 1, 1);
  asm volatile("s_waitcnt vmcnt(4)" ::: "memory");   // tile0 landed
  __builtin_amdgcn_s_barrier();

  constexpr int NI = NT / 2;
#pragma unroll 1
  for (int i = 0; i < NI - 1; ++i) {
    const int O1 = 2 * i + 1, E2 = 2 * i + 2, O2 = 2 * i + 3;
    {   // ===== tile E = 2i (buf0), phases 1-4 =====
      bfrag8 a0[4][2], a1[4][2], b0[2][2], b1[2][2];
      RD_A4(a0, 0, 0); RD_B2(b0, 0, 0); STG_A(0, 1, O1);      // ph1: 12 rd
      PH_MID; MFMAQ(a0, b0, 0, 0); PH_END;
      RD_B2(b1, 0, 2); STG_A(1, 1, O1);                        // ph2: 4 rd
      PH_MID; MFMAQ(a0, b1, 0, 2); PH_END;
      RD_A4(a1, 0, 4); STG_B(0, 0, E2);                        // ph3: 8 rd
      PH_MID; MFMAQ(a1, b1, 4, 2); PH_END;
      STG_B(1, 0, E2);                                         // ph4: 0 rd
      PH_MID; MFMAQ(a1, b0, 4, 0);
      __builtin_amdgcn_s_setprio(0);
      __builtin_amdgcn_sched_barrier(0);
      asm volatile("s_waitcnt vmcnt(4)" ::: "memory");         // tile O landed
      __builtin_amdgcn_s_barrier();
    }
    {   // ===== tile O = 2i+1 (buf1), phases 5-8 =====
      bfrag8 a0[4][2], a1[4][2], b0[2][2], b1[2][2];
      RD_A4(a0, 16384, 0); RD_B2(b0, 16384, 0); STG_A(0, 0, E2);  // ph5
      PH_MID; MFMAQ(a0, b0, 0, 0); PH_END;
      RD_B2(b1, 16384, 2); STG_A(1, 0, E2);                       // ph6
      PH_MID; MFMAQ(a0, b1, 0, 2); PH_END;
      RD_A4(a1, 16384, 4); STG_B(0, 1, O2);                       // ph7
      PH_MID; MFMAQ(a1, b1, 4, 2); PH_END;
      STG_B(1, 1, O2);                                            // ph8
      PH_MID; MFMAQ(a1, b0, 4, 0);
      __builtin_amdgcn_s_setprio(0);
      __builtin_amdgcn_sched_barrier(0);
      asm volatile("s_waitcnt vmcnt(4)" ::: "memory");            // E2 landed
      __builtin_amdgcn_s_barrier();
    }
  }
  {   // ===== peeled last iteration: tiles NT-2 (buf0), NT-1 (buf1) =====
    const int O1 = NT - 1;
    {
      bfrag8 a0[4][2], a1[4][2], b0[2][2], b1[2][2];
      RD_A4(a0, 0, 0); RD_B2(b0, 0, 0); STG_A(0, 1, O1);
      PH_MID; MFMAQ(a0, b0, 0, 0); PH_END;
      RD_B2(b1, 0, 2); STG_A(1, 1, O1);
      PH_MID; MFMAQ(a0, b1, 0, 2); PH_END;
      RD_A4(a1, 0, 4);
      PH_MID; MFMAQ(a1, b1, 4, 2); PH_END;
      PH_MID; MFMAQ(a1, b0, 4, 0);
      __builtin_amdgcn_s_setprio(0);
      __builtin_amdgcn_sched_barrier(0);
      asm volatile("s_waitcnt vmcnt(0)" ::: "memory");   // drain: tile NT-1 landed
      __builtin_amdgcn_s_barrier();
    }
    {
      bfrag8 a0[4][2], a1[4][2], b0[2][2], b1[2][2];
      RD_A4(a0, 16384, 0); RD_B2(b0, 16384, 0);
      PH_MID; MFMAQ(a0, b0, 0, 0); PH_END;
      RD_B2(b1, 16384, 2);
      PH_MID; MFMAQ(a0, b1, 0, 2); PH_END;
      RD_A4(a1, 16384, 4);
      PH_MID; MFMAQ(a1, b1, 4, 2); PH_END;
      PH_MID; MFMAQ(a1, b0, 4, 0);
      __builtin_amdgcn_s_setprio(0);
    }
  }
#undef PH_MID
#undef PH_END
#undef MFMAQ
#undef RD_A4
#undef RD_B2
#undef STG_A
#undef STG_B
}

// ============ fused QKV projection on the 256^2 core: 384 jobs =============
__global__ __launch_bounds__(512, 2) void proj3_256(
    const unsigned short* __restrict__ Xq, const unsigned short* __restrict__ Wqb,
    const unsigned short* __restrict__ Xk, const unsigned short* __restrict__ Wkb,
    const unsigned short* __restrict__ Xv, const unsigned short* __restrict__ Wvb,
    unsigned short* __restrict__ Qb, unsigned short* __restrict__ Kb,
    unsigned short* __restrict__ Vt) {
  extern __shared__ unsigned short smem[];
  unsigned short* As = smem;
  unsigned short* Bs = smem + 32768;

  const int pid = blockIdx.x;
  const int p2  = (pid & 7) * 48 + (pid >> 3);  // XCD-contiguous (384 = 8*48)
  const int g   = p2 >> 7;                      // 0:Q 1:K 2:Vt
  const int within = p2 & 127;

  const unsigned short* A; const unsigned short* B; unsigned short* C;
  long bm, bn; int ldc_;
  if (g == 0)      { A = Xq;  B = Wqb; C = Qb; }
  else if (g == 1) { A = Xk;  B = Wkb; C = Kb; }
  else             { A = Wvb; B = Xv;  C = Vt; }
  if (g < 2) { bm = (long)(within >> 2) * 256; bn = (long)(within & 3)  * 256; ldc_ = 1024; }
  else       { bm = (long)(within >> 5) * 256; bn = (long)(within & 31) * 256; ldc_ = 8192; }

  facc4 acc[8][4] = {};
  core256<HID / 64>(A + bm * 1024, B + bn * 1024, 1024, 1024, As, Bs, acc);

  // Epilogue: C/D layout col=lane&15, row=(lane>>4)*4+reg  [m89-verified]
  const int lane = threadIdx.x & 63, wave = threadIdx.x >> 6;
  const int wm = wave >> 2, wn = wave & 3;
  const int ln = lane & 15, lq = lane >> 4;
#pragma unroll
  for (int m = 0; m < 8; ++m)
#pragma unroll
    for (int n = 0; n < 4; ++n) {
      const long mm = bm + wm * 128 + m * 16 + lq * 4;
      const long nn = bn + wn * 64 + n * 16 + ln;
#pragma unroll
      for (int r = 0; r < 4; ++r)
        C[(mm + r) * (long)ldc_ + nn] = f2b(acc[m][n][r]);
    }
}

// ============ scores on the 256^2 core: P = exp(Q.K^T/32), lsum += ========
__global__ __launch_bounds__(512, 2) void scores256(
    const unsigned short* __restrict__ Q, const unsigned short* __restrict__ Kb,
    unsigned short* __restrict__ P, float* __restrict__ lsum) {
  extern __shared__ unsigned short smem[];
  unsigned short* As = smem;
  unsigned short* Bs = smem + 32768;

  const long z = blockIdx.z;
  const int pid = blockIdx.y * 8 + blockIdx.x;
  const int p2  = (pid & 7) * 8 + (pid >> 3);   // XCD gets one bm row-panel
  const long bm = (long)(p2 >> 3) * 256;
  const long bn = (long)(p2 & 7) * 256;

  const long SH = (long)SLEN * HID, SS = (long)SLEN * SLEN;
  facc4 acc[8][4] = {};
  core256<HID / 64>(Q + z * SH + bm * 1024, Kb + z * SH + bn * 1024, 1024, 1024,
                    As, Bs, acc);

  unsigned short* Pz = P + z * SS;
  float* lz = lsum + z * SLEN;
  const int lane = threadIdx.x & 63, wave = threadIdx.x >> 6;
  const int wm = wave >> 2, wn = wave & 3;
  const int ln = lane & 15, lq = lane >> 4;
#pragma unroll
  for (int m = 0; m < 8; ++m) {
#pragma unroll
    for (int r = 0; r < 4; ++r) {
      const long q = bm + wm * 128 + m * 16 + lq * 4 + r;
      float rowsum = 0.f;
#pragma unroll
      for (int n = 0; n < 4; ++n) {
        const long kcol = bn + wn * 64 + n * 16 + ln;
        float e = __expf(acc[m][n][r] * 0.03125f);
        Pz[q * (long)SLEN + kcol] = f2b(e);
        rowsum += e;
      }
      rowsum += __shfl_xor(rowsum, 1, 64);
      rowsum += __shfl_xor(rowsum, 2, 64);
      rowsum += __shfl_xor(rowsum, 4, 64);
      rowsum += __shfl_xor(rowsum, 8, 64);
      if (ln == 0) atomicAdd(&lz[q], rowsum);
    }
  }
}

// ---------------- bf16 NT GEMM (r5-proven 128^2 core), PV only -------------
template <int MODE, typename OutT>
__global__ __launch_bounds__(256) void gemm_nt(
    const unsigned short* __restrict__ A, const unsigned short* __restrict__ B,
    OutT* __restrict__ C, int K, int lda, int ldb, int ldc,
    long aStrideZ, long bStrideZ, long cStrideZ, float alpha,
    float* __restrict__ lsum) {
  A += (long)blockIdx.z * aStrideZ;
  B += (long)blockIdx.z * bStrideZ;
  C += (long)blockIdx.z * cStrideZ;
  const long lz = (long)blockIdx.z * SLEN;

  const int nbm = gridDim.x, nbn = gridDim.y;
  const int nb  = nbm * nbn;
  const int pid = blockIdx.y * nbm + blockIdx.x;
  const int p2  = (pid & 7) * (nb >> 3) + (pid >> 3);
  const int GROUP = 4;
  const int gsize = GROUP * nbn;
  const int gid   = p2 / gsize;
  const int rem   = p2 - gid * gsize;
  const long bm = (long)(gid * GROUP + (rem & (GROUP - 1))) * 128;
  const long bn = (long)(rem >> 2) * 128;

  __shared__ __align__(16) unsigned short As[128 * 64];
  __shared__ __align__(16) unsigned short Bs[128 * 64];

  const int tid  = threadIdx.x;
  const int lane = tid & 63;
  const int wave = tid >> 6;
  const int wr   = (wave >> 1) * 64;
  const int wc   = (wave & 1) * 64;
  const int ln   = lane & 15;
  const int lq   = lane >> 4;
  const int swz  = ln & 7;

  facc4 acc[4][4] = {};

  const unsigned short* ap[4]; const unsigned short* bp[4];
  unsigned short* asd[4]; unsigned short* bsd[4];
#pragma unroll
  for (int j = 0; j < 4; ++j) {
    const int c   = j * 256 + tid;
    const int row = c >> 3;
    const int src = ((c & 7) ^ (row & 7)) * 8;
    ap[j]  = A + (bm + row) * (long)lda + src;
    bp[j]  = B + (bn + row) * (long)ldb + src;
    asd[j] = &As[c * 8];
    bsd[j] = &Bs[c * 8];
  }

  for (int k0 = 0; k0 < K; k0 += 64) {
#pragma unroll
    for (int j = 0; j < 4; ++j) { gl_lds16(ap[j], asd[j]); ap[j] += 64; }
#pragma unroll
    for (int j = 0; j < 4; ++j) { gl_lds16(bp[j], bsd[j]); bp[j] += 64; }
    __syncthreads();

#pragma unroll
    for (int kk = 0; kk < 2; ++kk) {
      bfrag8 af[4], bfr[4];
#pragma unroll
      for (int i = 0; i < 4; ++i)
        af[i] = *(const bfrag8*)&As[(wr + i * 16 + ln) * 64 + ((kk * 4 + lq) ^ swz) * 8];
#pragma unroll
      for (int j = 0; j < 4; ++j)
        bfr[j] = *(const bfrag8*)&Bs[(wc + j * 16 + ln) * 64 + ((kk * 4 + lq) ^ swz) * 8];
#pragma unroll
      for (int i = 0; i < 4; ++i)
#pragma unroll
        for (int j = 0; j < 4; ++j)
          acc[i][j] = __builtin_amdgcn_mfma_f32_16x16x32_bf16(af[i], bfr[j], acc[i][j], 0, 0, 0);
    }
    __syncthreads();
  }

  if constexpr (MODE == 1) {
#pragma unroll
    for (int i = 0; i < 4; ++i) {
#pragma unroll
      for (int r = 0; r < 4; ++r) {
        const long m = bm + wr + i * 16 + lq * 4 + r;
        float rowsum = 0.f;
#pragma unroll
        for (int j = 0; j < 4; ++j) {
          const long n = bn + wc + j * 16 + ln;
          float e = __expf(acc[i][j][r] * alpha);
          C[m * (long)ldc + n] = (OutT)f2b(e);
          rowsum += e;
        }
        rowsum += __shfl_xor(rowsum, 1, 64);
        rowsum += __shfl_xor(rowsum, 2, 64);
        rowsum += __shfl_xor(rowsum, 4, 64);
        rowsum += __shfl_xor(rowsum, 8, 64);
        if (ln == 0) atomicAdd(&lsum[lz + m], rowsum);
      }
    }
  } else {
    float inv[16];
#pragma unroll
    for (int i = 0; i < 4; ++i)
#pragma unroll
      for (int r = 0; r < 4; ++r)
        inv[i * 4 + r] = 1.0f / lsum[lz + bm + wr + i * 16 + lq * 4 + r];
#pragma unroll
    for (int i = 0; i < 4; ++i)
#pragma unroll
      for (int j = 0; j < 4; ++j) {
        const long m = bm + wr + i * 16 + lq * 4;
        const long n = bn + wc + j * 16 + ln;
#pragma unroll
        for (int r = 0; r < 4; ++r)
          ((float*)C)[(m + r) * (long)ldc + n] = acc[i][j][r] * inv[i * 4 + r];
      }
  }
}

extern "C" void kernel_launch(void* const* d_in, const int* in_sizes, int n_in,
                              void* d_out, int out_size, void* d_ws, size_t ws_size,
                              hipStream_t stream) {
  const float* q_in = (const float*)d_in[0];
  const float* k_in = (const float*)d_in[1];
  const float* v_in = (const float*)d_in[2];
  const float* wq   = (const float*)d_in[3];
  const float* wk   = (const float*)d_in[4];
  const float* wv   = (const float*)d_in[5];
  float* out = (float*)d_out;

  const long NXH = (long)BATCH * SLEN * HID;   // 8,388,608
  const long NW  = (long)HID * HID;            // 1,048,576
  const long SH  = (long)SLEN * HID;           // per-batch q/k/v stride
  const long SS  = (long)SLEN * SLEN;          // per-batch score stride

  unsigned short* ws = (unsigned short*)d_ws;
  unsigned short* Xq  = ws;              // cast dst region is contiguous Xq..Wvb
  unsigned short* Xk  = Xq  + NXH;
  unsigned short* Xv  = Xk  + NXH;
  unsigned short* Wqb = Xv  + NXH;
  unsigned short* Wkb = Wqb + NW;
  unsigned short* Wvb = Wkb + NW;
  unsigned short* Qb  = Wvb + NW;
  unsigned short* Kb  = Qb  + NXH;
  unsigned short* Vt  = Kb  + NXH;       // Vt[h][b*S+s], ld = 8192
  float*          lsum = (float*)(Vt + NXH);   // 8192 fp32 row sums
  unsigned short* P   = Xq;              // 16.8M elems, aliases Xq+Xk (dead by then)

  static bool attr_done = false;
  if (!attr_done) {
    hipFuncSetAttribute(reinterpret_cast<const void*>(proj3_256),
                        hipFuncAttributeMaxDynamicSharedMemorySize, 131072);
    hipFuncSetAttribute(reinterpret_cast<const void*>(scores256),
                        hipFuncAttributeMaxDynamicSharedMemorySize, 131072);
    attr_done = true;
  }

  // 1. fused cast (28.3M elems) + lsum zeroing
  cast_all<<<dim3(27648), dim3(256), 0, stream>>>(q_in, k_in, v_in, wq, wk, wv,
                                                  (us4*)ws, lsum);

  // 2. all three projections, 256^2 8-phase core (384 blocks)
  proj3_256<<<dim3(384), dim3(512), 131072, stream>>>(
      Xq, Wqb, Xk, Wkb, Xv, Wvb, Qb, Kb, Vt);

  // 3. scores+exp+rowsums, 256^2 core (256 blocks = 1/CU)
  scores256<<<dim3(8, 8, BATCH), dim3(512), 131072, stream>>>(Qb, Kb, P, lsum);

  // 4. out[b][q][h] = (1/lsum[b,q]) * sum_k P[b,q,k] * Vt[h][b*S+k]
  gemm_nt<2, float><<<dim3(16, 8, BATCH), dim3(256), 0, stream>>>(
      P, Vt, out, SLEN, SLEN, BATCH * SLEN, HID, SS, SLEN, SH, 1.0f, lsum);
}

// Round 4
// 277.652 us; speedup vs baseline: 1.0732x; 1.0204x over previous
//
#include <hip/hip_runtime.h>
#include <hip/hip_bf16.h>
#include <stdint.h>

// Problem constants: B=4, S=2048, H=1024
#define BATCH 4
#define SLEN  2048
#define HID   1024

typedef __attribute__((ext_vector_type(8))) short bfrag8;   // 8 bf16 (4 VGPRs)
typedef __attribute__((ext_vector_type(4))) float facc4;    // 4 fp32 acc
typedef __attribute__((ext_vector_type(4))) unsigned short us4;

__device__ __forceinline__ unsigned short f2b(float f) {
  union { float f; unsigned int i; } x; x.f = f;
  unsigned int r = x.i + 0x7FFFu + ((x.i >> 16) & 1u);  // RNE
  return (unsigned short)(r >> 16);
}

__device__ __forceinline__ void gl_lds16(const void* g, void* l) {
  __builtin_amdgcn_global_load_lds(
      (const __attribute__((address_space(1))) void*)g,
      (__attribute__((address_space(3))) void*)l, 16, 0, 0);
}

// ------------- fused fp32 -> bf16 cast of all six inputs + lsum zero -------
// At BW ceiling: 170 MB / ~27 us = 6.3 TB/s.
__global__ __launch_bounds__(256) void cast_all(
    const float* __restrict__ q, const float* __restrict__ k,
    const float* __restrict__ v, const float* __restrict__ wq,
    const float* __restrict__ wk, const float* __restrict__ wv,
    us4* __restrict__ dst, float* __restrict__ lsum) {
  if (blockIdx.x < 8) {
    float4 z = {0.f, 0.f, 0.f, 0.f};
    ((float4*)lsum)[blockIdx.x * 256 + threadIdx.x] = z;
  }
  const long i = (long)blockIdx.x * 256 + threadIdx.x;
  const long S1 = 2097152, S2 = 4194304, S3 = 6291456,
             S4 = 6553600, S5 = 6815744;
  const float4* src; long off;
  if (i < S2) {
    if (i < S1) { src = (const float4*)q;  off = i; }
    else        { src = (const float4*)k;  off = i - S1; }
  } else if (i < S3) { src = (const float4*)v;  off = i - S2; }
  else if   (i < S4) { src = (const float4*)wq; off = i - S3; }
  else if   (i < S5) { src = (const float4*)wk; off = i - S4; }
  else               { src = (const float4*)wv; off = i - S5; }
  float4 x = src[off];
  us4 o;
  o.x = f2b(x.x); o.y = f2b(x.y); o.z = f2b(x.z); o.w = f2b(x.w);
  dst[i] = o;
}

// ============ fused QKV projection: 3 bf16 NT GEMMs in ONE dispatch ========
// REVERTED to the r0 harness-proven 128^2 core (56.7 us, 912 TF, MfmaUtil 37%).
// r1-r3 post-mortem: three explicit 256^2 pipelines (flood / read-ahead /
// m201-cadence) all measured 27-32% MfmaUtil and 61-78 us — at 1 block/CU
// (128 KiB LDS) the 384-block grid runs 1.5 scheduling rounds (round 2 half
// idle), and the per-block throughput never beat this core's implicit
// cross-block overlap at 2-3 blocks/CU. Jobs 0-511: Q=Xq.Wq^T; 512-1023:
// K=Xk.Wk^T; 1024-1535: Vt=Wv.Xv^T (ldc 8192). XCD remap (pid&7)*192+(pid>>3).
__global__ __launch_bounds__(256) void proj3(
    const unsigned short* __restrict__ Xq, const unsigned short* __restrict__ Wqb,
    const unsigned short* __restrict__ Xk, const unsigned short* __restrict__ Wkb,
    const unsigned short* __restrict__ Xv, const unsigned short* __restrict__ Wvb,
    unsigned short* __restrict__ Qb, unsigned short* __restrict__ Kb,
    unsigned short* __restrict__ Vt) {
  const int pid = blockIdx.x;
  const int p2     = (pid & 7) * 192 + (pid >> 3);  // XCD-contiguous
  const int g      = p2 >> 9;                       // 0:Q 1:K 2:Vt
  const int within = p2 & 511;

  const unsigned short* A; const unsigned short* B; unsigned short* C;
  long bm, bn; int ldc_;
  if (g == 0)      { A = Xq; B = Wqb; C = Qb; }
  else if (g == 1) { A = Xk; B = Wkb; C = Kb; }
  else             { A = Wvb; B = Xv; C = Vt; }
  if (g < 2) {   // nbm=64, nbn=8, GROUP=4
    const int gid = within >> 5, rem = within & 31;
    bm = (long)(gid * 4 + (rem & 3)) * 128;
    bn = (long)(rem >> 2) * 128;
    ldc_ = 1024;
  } else {       // nbm=8, nbn=64, GROUP=4
    const int gid = within >> 8, rem = within & 255;
    bm = (long)(gid * 4 + (rem & 3)) * 128;
    bn = (long)(rem >> 2) * 128;
    ldc_ = 8192;
  }

  __shared__ __align__(16) unsigned short As[128 * 64];
  __shared__ __align__(16) unsigned short Bs[128 * 64];

  const int tid  = threadIdx.x;
  const int lane = tid & 63;
  const int wave = tid >> 6;
  const int wr   = (wave >> 1) * 64;
  const int wc   = (wave & 1) * 64;
  const int ln   = lane & 15;
  const int lq   = lane >> 4;
  const int swz  = ln & 7;

  facc4 acc[4][4] = {};

  const unsigned short* ap[4]; const unsigned short* bp[4];
  unsigned short* asd[4]; unsigned short* bsd[4];
#pragma unroll
  for (int j = 0; j < 4; ++j) {
    const int c   = j * 256 + tid;
    const int row = c >> 3;
    const int src = ((c & 7) ^ (row & 7)) * 8;
    ap[j]  = A + (bm + row) * 1024 + src;
    bp[j]  = B + (bn + row) * 1024 + src;
    asd[j] = &As[c * 8];
    bsd[j] = &Bs[c * 8];
  }

  for (int k0 = 0; k0 < 1024; k0 += 64) {
#pragma unroll
    for (int j = 0; j < 4; ++j) { gl_lds16(ap[j], asd[j]); ap[j] += 64; }
#pragma unroll
    for (int j = 0; j < 4; ++j) { gl_lds16(bp[j], bsd[j]); bp[j] += 64; }
    __syncthreads();

#pragma unroll
    for (int kk = 0; kk < 2; ++kk) {
      bfrag8 af[4], bfr[4];
#pragma unroll
      for (int i = 0; i < 4; ++i)
        af[i] = *(const bfrag8*)&As[(wr + i * 16 + ln) * 64 + ((kk * 4 + lq) ^ swz) * 8];
#pragma unroll
      for (int j = 0; j < 4; ++j)
        bfr[j] = *(const bfrag8*)&Bs[(wc + j * 16 + ln) * 64 + ((kk * 4 + lq) ^ swz) * 8];
#pragma unroll
      for (int i = 0; i < 4; ++i)
#pragma unroll
        for (int j = 0; j < 4; ++j)
          acc[i][j] = __builtin_amdgcn_mfma_f32_16x16x32_bf16(af[i], bfr[j], acc[i][j], 0, 0, 0);
    }
    __syncthreads();
  }

  // Epilogue: C/D layout col=lane&15, row=(lane>>4)*4+reg  [m89-verified]
#pragma unroll
  for (int i = 0; i < 4; ++i)
#pragma unroll
    for (int j = 0; j < 4; ++j) {
      const long m = bm + wr + i * 16 + lq * 4;
      const long n = bn + wc + j * 16 + ln;
#pragma unroll
      for (int r = 0; r < 4; ++r)
        C[(m + r) * (long)ldc_ + n] = f2b(acc[i][j][r]);
    }
}

// ================= 256x256 / BK=64 core — 8-phase (kept for scores) =======
// Kept EXACTLY as benched in r3's 283-us composition: scores256 (256 blocks
// = exact 1/CU packing) is where the 256^2 tile pays (bigger tile amortizes
// the heavy exp/store epilogue; perfect packing). Not used for proj.
template <int NT>
__device__ __forceinline__ void core256(
    const unsigned short* __restrict__ A, const unsigned short* __restrict__ B,
    const int lda, const int ldb,
    unsigned short* __restrict__ As, unsigned short* __restrict__ Bs,
    facc4 (&acc)[8][4]) {
  const int tid  = threadIdx.x;          // 0..511
  const int lane = tid & 63;
  const int wave = tid >> 6;             // 0..7
  const int wm = wave >> 2;              // 0..1
  const int wn = wave & 3;               // 0..3
  const int ln = lane & 15;
  const int lq = lane >> 4;
  const int swz = ln & 7;

  const int row0 = tid >> 3;
  const int blk  = (tid & 7) ^ (row0 & 7);
  const unsigned short* pA = A + (long)row0 * lda + blk * 8;
  const unsigned short* pB = B + (long)row0 * ldb + blk * 8;
  const long a64 = 64l * lda, b64 = 64l * ldb;
  unsigned short* dA = As + tid * 8;
  unsigned short* dB = Bs + tid * 8;

#define STG_A(h, b, t) do { const unsigned short* g_ = pA + (h) * (a64 * 2) + (long)(t) * 64; \
    gl_lds16(g_,       dA + (b) * 16384 + (h) * 8192); \
    gl_lds16(g_ + a64, dA + (b) * 16384 + (h) * 8192 + 4096); } while (0)
#define STG_B(h, b, t) do { const unsigned short* g_ = pB + (h) * (b64 * 2) + (long)(t) * 64; \
    gl_lds16(g_,       dB + (b) * 16384 + (h) * 8192); \
    gl_lds16(g_ + b64, dB + (b) * 16384 + (h) * 8192 + 4096); } while (0)

  const int o0 = (lq ^ swz) * 8;
  const int o1 = ((4 + lq) ^ swz) * 8;
  const int aOfs = wm * 8192 + ln * 64;
  const int bOfs = (wn >> 1) * 8192 + ((wn & 1) * 64 + ln) * 64;

#define RD_A4(dst, bufb, mb) do { \
  _Pragma("unroll") for (int m_ = 0; m_ < 4; ++m_) { \
    dst[m_][0] = *(const bfrag8*)(As + (bufb) + aOfs + ((mb) + m_) * 1024 + o0); \
    dst[m_][1] = *(const bfrag8*)(As + (bufb) + aOfs + ((mb) + m_) * 1024 + o1); \
  } } while (0)
#define RD_B2(dst, bufb, nb) do { \
  _Pragma("unroll") for (int n_ = 0; n_ < 2; ++n_) { \
    dst[n_][0] = *(const bfrag8*)(Bs + (bufb) + bOfs + ((nb) + n_) * 1024 + o0); \
    dst[n_][1] = *(const bfrag8*)(Bs + (bufb) + bOfs + ((nb) + n_) * 1024 + o1); \
  } } while (0)

#define MFMAQ(AF, BF, MO, NO) do { \
  _Pragma("unroll") for (int m_ = 0; m_ < 4; ++m_) \
  _Pragma("unroll") for (int n_ = 0; n_ < 2; ++n_) { \
    acc[(MO)+m_][(NO)+n_] = __builtin_amdgcn_mfma_f32_16x16x32_bf16( \
        AF[m_][0], BF[n_][0], acc[(MO)+m_][(NO)+n_], 0, 0, 0); \
    acc[(MO)+m_][(NO)+n_] = __builtin_amdgcn_mfma_f32_16x16x32_bf16( \
        AF[m_][1], BF[n_][1], acc[(MO)+m_][(NO)+n_], 0, 0, 0); \
  } } while (0)

#define PH_MID \
  __builtin_amdgcn_s_barrier(); \
  asm volatile("s_waitcnt lgkmcnt(0)" ::: "memory"); \
  __builtin_amdgcn_sched_barrier(0); \
  __builtin_amdgcn_s_setprio(1)
#define PH_END \
  __builtin_amdgcn_s_setprio(0); \
  __builtin_amdgcn_sched_barrier(0); \
  __builtin_amdgcn_s_barrier()

  STG_A(0, 0, 0); STG_A(1, 0, 0); STG_B(0, 0, 0); STG_B(1, 0, 0);
  STG_B(0, 1, 1); STG_B(1, 1, 1);
  asm volatile("s_waitcnt vmcnt(4)" ::: "memory");
  __builtin_amdgcn_s_barrier();

  constexpr int NI = NT / 2;
#pragma unroll 1
  for (int i = 0; i < NI - 1; ++i) {
    const int O1 = 2 * i + 1, E2 = 2 * i + 2, O2 = 2 * i + 3;
    {
      bfrag8 a0[4][2], a1[4][2], b0[2][2], b1[2][2];
      RD_A4(a0, 0, 0); RD_B2(b0, 0, 0); STG_A(0, 1, O1);
      PH_MID; MFMAQ(a0, b0, 0, 0); PH_END;
      RD_B2(b1, 0, 2); STG_A(1, 1, O1);
      PH_MID; MFMAQ(a0, b1, 0, 2); PH_END;
      RD_A4(a1, 0, 4); STG_B(0, 0, E2);
      PH_MID; MFMAQ(a1, b1, 4, 2); PH_END;
      STG_B(1, 0, E2);
      PH_MID; MFMAQ(a1, b0, 4, 0);
      __builtin_amdgcn_s_setprio(0);
      __builtin_amdgcn_sched_barrier(0);
      asm volatile("s_waitcnt vmcnt(4)" ::: "memory");
      __builtin_amdgcn_s_barrier();
    }
    {
      bfrag8 a0[4][2], a1[4][2], b0[2][2], b1[2][2];
      RD_A4(a0, 16384, 0); RD_B2(b0, 16384, 0); STG_A(0, 0, E2);
      PH_MID; MFMAQ(a0, b0, 0, 0); PH_END;
      RD_B2(b1, 16384, 2); STG_A(1, 0, E2);
      PH_MID; MFMAQ(a0, b1, 0, 2); PH_END;
      RD_A4(a1, 16384, 4); STG_B(0, 1, O2);
      PH_MID; MFMAQ(a1, b1, 4, 2); PH_END;
      STG_B(1, 1, O2);
      PH_MID; MFMAQ(a1, b0, 4, 0);
      __builtin_amdgcn_s_setprio(0);
      __builtin_amdgcn_sched_barrier(0);
      asm volatile("s_waitcnt vmcnt(4)" ::: "memory");
      __builtin_amdgcn_s_barrier();
    }
  }
  {
    const int O1 = NT - 1;
    {
      bfrag8 a0[4][2], a1[4][2], b0[2][2], b1[2][2];
      RD_A4(a0, 0, 0); RD_B2(b0, 0, 0); STG_A(0, 1, O1);
      PH_MID; MFMAQ(a0, b0, 0, 0); PH_END;
      RD_B2(b1, 0, 2); STG_A(1, 1, O1);
      PH_MID; MFMAQ(a0, b1, 0, 2); PH_END;
      RD_A4(a1, 0, 4);
      PH_MID; MFMAQ(a1, b1, 4, 2); PH_END;
      PH_MID; MFMAQ(a1, b0, 4, 0);
      __builtin_amdgcn_s_setprio(0);
      __builtin_amdgcn_sched_barrier(0);
      asm volatile("s_waitcnt vmcnt(0)" ::: "memory");
      __builtin_amdgcn_s_barrier();
    }
    {
      bfrag8 a0[4][2], a1[4][2], b0[2][2], b1[2][2];
      RD_A4(a0, 16384, 0); RD_B2(b0, 16384, 0);
      PH_MID; MFMAQ(a0, b0, 0, 0); PH_END;
      RD_B2(b1, 16384, 2);
      PH_MID; MFMAQ(a0, b1, 0, 2); PH_END;
      RD_A4(a1, 16384, 4);
      PH_MID; MFMAQ(a1, b1, 4, 2); PH_END;
      PH_MID; MFMAQ(a1, b0, 4, 0);
      __builtin_amdgcn_s_setprio(0);
    }
  }
#undef PH_MID
#undef PH_END
#undef MFMAQ
#undef RD_A4
#undef RD_B2
#undef STG_A
#undef STG_B
}

// ============ scores on the 256^2 core: P = exp(Q.K^T/32), lsum += ========
// 256 blocks total (8x8 tiles x 4 batches) = exactly 1 per CU.
__global__ __launch_bounds__(512, 2) void scores256(
    const unsigned short* __restrict__ Q, const unsigned short* __restrict__ Kb,
    unsigned short* __restrict__ P, float* __restrict__ lsum) {
  extern __shared__ unsigned short smem[];
  unsigned short* As = smem;
  unsigned short* Bs = smem + 32768;

  const long z = blockIdx.z;
  const int pid = blockIdx.y * 8 + blockIdx.x;
  const int p2  = (pid & 7) * 8 + (pid >> 3);   // XCD gets one bm row-panel
  const long bm = (long)(p2 >> 3) * 256;
  const long bn = (long)(p2 & 7) * 256;

  const long SH = (long)SLEN * HID, SS = (long)SLEN * SLEN;
  facc4 acc[8][4] = {};
  core256<HID / 64>(Q + z * SH + bm * 1024, Kb + z * SH + bn * 1024, 1024, 1024,
                    As, Bs, acc);

  unsigned short* Pz = P + z * SS;
  float* lz = lsum + z * SLEN;
  const int lane = threadIdx.x & 63, wave = threadIdx.x >> 6;
  const int wm = wave >> 2, wn = wave & 3;
  const int ln = lane & 15, lq = lane >> 4;
#pragma unroll
  for (int m = 0; m < 8; ++m) {
#pragma unroll
    for (int r = 0; r < 4; ++r) {
      const long q = bm + wm * 128 + m * 16 + lq * 4 + r;
      float rowsum = 0.f;
#pragma unroll
      for (int n = 0; n < 4; ++n) {
        const long kcol = bn + wn * 64 + n * 16 + ln;
        float e = __expf(acc[m][n][r] * 0.03125f);
        Pz[q * (long)SLEN + kcol] = f2b(e);
        rowsum += e;
      }
      rowsum += __shfl_xor(rowsum, 1, 64);
      rowsum += __shfl_xor(rowsum, 2, 64);
      rowsum += __shfl_xor(rowsum, 4, 64);
      rowsum += __shfl_xor(rowsum, 8, 64);
      if (ln == 0) atomicAdd(&lz[q], rowsum);
    }
  }
}

// ---------------- bf16 NT GEMM (r5-proven 128^2 core), PV only -------------
template <int MODE, typename OutT>
__global__ __launch_bounds__(256) void gemm_nt(
    const unsigned short* __restrict__ A, const unsigned short* __restrict__ B,
    OutT* __restrict__ C, int K, int lda, int ldb, int ldc,
    long aStrideZ, long bStrideZ, long cStrideZ, float alpha,
    float* __restrict__ lsum) {
  A += (long)blockIdx.z * aStrideZ;
  B += (long)blockIdx.z * bStrideZ;
  C += (long)blockIdx.z * cStrideZ;
  const long lz = (long)blockIdx.z * SLEN;

  const int nbm = gridDim.x, nbn = gridDim.y;
  const int nb  = nbm * nbn;
  const int pid = blockIdx.y * nbm + blockIdx.x;
  const int p2  = (pid & 7) * (nb >> 3) + (pid >> 3);
  const int GROUP = 4;
  const int gsize = GROUP * nbn;
  const int gid   = p2 / gsize;
  const int rem   = p2 - gid * gsize;
  const long bm = (long)(gid * GROUP + (rem & (GROUP - 1))) * 128;
  const long bn = (long)(rem >> 2) * 128;

  __shared__ __align__(16) unsigned short As[128 * 64];
  __shared__ __align__(16) unsigned short Bs[128 * 64];

  const int tid  = threadIdx.x;
  const int lane = tid & 63;
  const int wave = tid >> 6;
  const int wr   = (wave >> 1) * 64;
  const int wc   = (wave & 1) * 64;
  const int ln   = lane & 15;
  const int lq   = lane >> 4;
  const int swz  = ln & 7;

  facc4 acc[4][4] = {};

  const unsigned short* ap[4]; const unsigned short* bp[4];
  unsigned short* asd[4]; unsigned short* bsd[4];
#pragma unroll
  for (int j = 0; j < 4; ++j) {
    const int c   = j * 256 + tid;
    const int row = c >> 3;
    const int src = ((c & 7) ^ (row & 7)) * 8;
    ap[j]  = A + (bm + row) * (long)lda + src;
    bp[j]  = B + (bn + row) * (long)ldb + src;
    asd[j] = &As[c * 8];
    bsd[j] = &Bs[c * 8];
  }

  for (int k0 = 0; k0 < K; k0 += 64) {
#pragma unroll
    for (int j = 0; j < 4; ++j) { gl_lds16(ap[j], asd[j]); ap[j] += 64; }
#pragma unroll
    for (int j = 0; j < 4; ++j) { gl_lds16(bp[j], bsd[j]); bp[j] += 64; }
    __syncthreads();

#pragma unroll
    for (int kk = 0; kk < 2; ++kk) {
      bfrag8 af[4], bfr[4];
#pragma unroll
      for (int i = 0; i < 4; ++i)
        af[i] = *(const bfrag8*)&As[(wr + i * 16 + ln) * 64 + ((kk * 4 + lq) ^ swz) * 8];
#pragma unroll
      for (int j = 0; j < 4; ++j)
        bfr[j] = *(const bfrag8*)&Bs[(wc + j * 16 + ln) * 64 + ((kk * 4 + lq) ^ swz) * 8];
#pragma unroll
      for (int i = 0; i < 4; ++i)
#pragma unroll
        for (int j = 0; j < 4; ++j)
          acc[i][j] = __builtin_amdgcn_mfma_f32_16x16x32_bf16(af[i], bfr[j], acc[i][j], 0, 0, 0);
    }
    __syncthreads();
  }

  if constexpr (MODE == 1) {
#pragma unroll
    for (int i = 0; i < 4; ++i) {
#pragma unroll
      for (int r = 0; r < 4; ++r) {
        const long m = bm + wr + i * 16 + lq * 4 + r;
        float rowsum = 0.f;
#pragma unroll
        for (int j = 0; j < 4; ++j) {
          const long n = bn + wc + j * 16 + ln;
          float e = __expf(acc[i][j][r] * alpha);
          C[m * (long)ldc + n] = (OutT)f2b(e);
          rowsum += e;
        }
        rowsum += __shfl_xor(rowsum, 1, 64);
        rowsum += __shfl_xor(rowsum, 2, 64);
        rowsum += __shfl_xor(rowsum, 4, 64);
        rowsum += __shfl_xor(rowsum, 8, 64);
        if (ln == 0) atomicAdd(&lsum[lz + m], rowsum);
      }
    }
  } else {
    float inv[16];
#pragma unroll
    for (int i = 0; i < 4; ++i)
#pragma unroll
      for (int r = 0; r < 4; ++r)
        inv[i * 4 + r] = 1.0f / lsum[lz + bm + wr + i * 16 + lq * 4 + r];
#pragma unroll
    for (int i = 0; i < 4; ++i)
#pragma unroll
      for (int j = 0; j < 4; ++j) {
        const long m = bm + wr + i * 16 + lq * 4;
        const long n = bn + wc + j * 16 + ln;
#pragma unroll
        for (int r = 0; r < 4; ++r)
          ((float*)C)[(m + r) * (long)ldc + n] = acc[i][j][r] * inv[i * 4 + r];
      }
  }
}

extern "C" void kernel_launch(void* const* d_in, const int* in_sizes, int n_in,
                              void* d_out, int out_size, void* d_ws, size_t ws_size,
                              hipStream_t stream) {
  const float* q_in = (const float*)d_in[0];
  const float* k_in = (const float*)d_in[1];
  const float* v_in = (const float*)d_in[2];
  const float* wq   = (const float*)d_in[3];
  const float* wk   = (const float*)d_in[4];
  const float* wv   = (const float*)d_in[5];
  float* out = (float*)d_out;

  const long NXH = (long)BATCH * SLEN * HID;   // 8,388,608
  const long NW  = (long)HID * HID;            // 1,048,576
  const long SH  = (long)SLEN * HID;           // per-batch q/k/v stride
  const long SS  = (long)SLEN * SLEN;          // per-batch score stride

  unsigned short* ws = (unsigned short*)d_ws;
  unsigned short* Xq  = ws;              // cast dst region is contiguous Xq..Wvb
  unsigned short* Xk  = Xq  + NXH;
  unsigned short* Xv  = Xk  + NXH;
  unsigned short* Wqb = Xv  + NXH;
  unsigned short* Wkb = Wqb + NW;
  unsigned short* Wvb = Wkb + NW;
  unsigned short* Qb  = Wvb + NW;
  unsigned short* Kb  = Qb  + NXH;
  unsigned short* Vt  = Kb  + NXH;       // Vt[h][b*S+s], ld = 8192
  float*          lsum = (float*)(Vt + NXH);   // 8192 fp32 row sums
  unsigned short* P   = Xq;              // 16.8M elems, aliases Xq+Xk (dead by then)

  static bool attr_done = false;
  if (!attr_done) {
    hipFuncSetAttribute(reinterpret_cast<const void*>(scores256),
                        hipFuncAttributeMaxDynamicSharedMemorySize, 131072);
    attr_done = true;
  }

  // 1. fused cast (28.3M elems) + lsum zeroing
  cast_all<<<dim3(27648), dim3(256), 0, stream>>>(q_in, k_in, v_in, wq, wk, wv,
                                                  (us4*)ws, lsum);

  // 2. all three projections in ONE dispatch (r0-proven 128^2, 1536 jobs)
  proj3<<<dim3(1536), dim3(256), 0, stream>>>(Xq, Wqb, Xk, Wkb, Xv, Wvb,
                                              Qb, Kb, Vt);

  // 3. scores+exp+rowsums, 256^2 core (256 blocks = 1/CU)
  scores256<<<dim3(8, 8, BATCH), dim3(512), 131072, stream>>>(Qb, Kb, P, lsum);

  // 4. out[b][q][h] = (1/lsum[b,q]) * sum_k P[b,q,k] * Vt[h][b*S+k]
  gemm_nt<2, float><<<dim3(16, 8, BATCH), dim3(256), 0, stream>>>(
      P, Vt, out, SLEN, SLEN, BATCH * SLEN, HID, SS, SLEN, SH, 1.0f, lsum);
}